// Round 4
// baseline (2792.926 us; speedup 1.0000x reference)
//
#include <hip/hip_runtime.h>
#include <hip/hip_bf16.h>

#define BB 256
#define SS 32
#define II 128
#define HH 256
#define LBL 200
#define NSUBS 491
#define NATOMS_N 8000
#define NMOL_N 600

typedef const float* fp;

__device__ __forceinline__ float sigm(float x) { return 1.f / (1.f + expf(-x)); }

// ---------------------------------------------------------------------------
// prep (10 blocks): idxv from mask, mstart via binary search, masked
// w_masklin, zero 4 h buffers
// ---------------------------------------------------------------------------
__global__ __launch_bounds__(256) void prep_kernel(
    const int* __restrict__ mask, int* __restrict__ idxv,
    const int* __restrict__ seg, int* __restrict__ mstart,
    fp w_masklin, fp ddi, float* __restrict__ mw,
    float* __restrict__ hzero)
{
  int bx = blockIdx.x, tid = threadIdx.x;
  if (bx == 0) {                         // idx[b] = clamp(sum(mask[b,:]) - 1)
    int s = 0;
    const int* mrow = mask + tid * SS;
    for (int t = 0; t < SS; ++t) s += mrow[t];
    s -= 1;
    if (s < 0) s = 0;
    if (s > SS - 1) s = SS - 1;
    idxv[tid] = s;
  } else if (bx == 1) {                  // mstart[m] = lower_bound(seg, m)
    for (int m = tid; m <= NMOL_N; m += 256) {
      if (m == NMOL_N) { mstart[m] = NATOMS_N; continue; }
      int lo = 0, hi = NATOMS_N;
      while (lo < hi) {
        int mid = (lo + hi) >> 1;
        if (seg[mid] < m) lo = mid + 1; else hi = mid;
      }
      mstart[m] = lo;
    }
  } else if (bx < 6) {                   // mw[s][l] = w_masklin[s][l]*ddi[l][s]
    for (int o = (bx - 2) * 256 + tid; o < NSUBS * LBL; o += 4 * 256) {
      int s = o / LBL, l = o - s * LBL;
      mw[o] = w_masklin[o] * ddi[l * NSUBS + s];
    }
  } else {                               // zero 4 h buffers (65536 floats each)
    float* p = hzero + (size_t)(bx - 6) * 65536;
    for (int o = tid; o < 65536; o += 256) p[o] = 0.f;
  }
}

// ---------------------------------------------------------------------------
// fully-fused MPNN: one block per molecule (<=14 atoms). Everything in
// LDS/registers; only output is mol[m][0:256] (segment_sum of round-2 result).
// ---------------------------------------------------------------------------
__global__ __launch_bounds__(256) void mpnn_mol(
    const int* __restrict__ fingerprints, fp embed_fp, fp adj,
    const int* __restrict__ mstart, fp w_g0, fp b_g0, fp w_g1, fp b_g1,
    float* __restrict__ mol)
{
  int m = blockIdx.x, tid = threadIdx.x;
  int a0 = mstart[m], a1 = mstart[m + 1];
  int sz = a1 - a0;
  if (sz < 0) sz = 0;
  if (sz > 14) sz = 14;

  __shared__ float v[14][260];           // atom features (cross-column reads)
  __shared__ float adjb[14][16];         // molecule adjacency block

#pragma unroll
  for (int i = 0; i < 14; ++i) {
    float val = 0.f;
    if (i < sz) {
      int f = fingerprints[a0 + i] & 1023;
      val = embed_fp[(size_t)f * HH + tid];
    }
    v[i][tid] = val;
  }
  if (tid < 224) {
    int i = tid >> 4, jj = tid & 15;
    float a = 0.f;
    if (i < sz && jj < sz)
      a = adj[(size_t)(a0 + i) * NATOMS_N + a0 + jj];
    adjb[i][jj] = a;
  }
  __syncthreads();

  float acc[14];
  for (int rd = 0; rd < 2; ++rd) {
    const float* wp0 = (rd ? w_g1 : w_g0) + tid;
#pragma unroll
    for (int i = 0; i < 14; ++i) acc[i] = 0.f;
    for (int k = 0; k < HH; k += 4) {
      float w0 = wp0[(size_t)k * HH];
      float w1 = wp0[(size_t)(k + 1) * HH];
      float w2 = wp0[(size_t)(k + 2) * HH];
      float w3 = wp0[(size_t)(k + 3) * HH];
#pragma unroll
      for (int i = 0; i < 14; ++i) {
        float4 vv = *(const float4*)&v[i][k];
        acc[i] = fmaf(vv.x, w0, acc[i]);
        acc[i] = fmaf(vv.y, w1, acc[i]);
        acc[i] = fmaf(vv.z, w2, acc[i]);
        acc[i] = fmaf(vv.w, w3, acc[i]);
      }
    }
    float bias = (rd ? b_g1 : b_g0)[tid];
    float hreg[14];
#pragma unroll
    for (int i = 0; i < 14; ++i) hreg[i] = fmaxf(acc[i] + bias, 0.f);
#pragma unroll
    for (int i = 0; i < 14; ++i) {
      float s = hreg[i];
#pragma unroll
      for (int jj = 0; jj < 14; ++jj) s = fmaf(adjb[i][jj], hreg[jj], s);
      acc[i] = s;
    }
    if (rd == 0) {
      __syncthreads();                   // all v reads done
#pragma unroll
      for (int i = 0; i < 14; ++i) v[i][tid] = acc[i];
      __syncthreads();
    }
  }
  float msum = 0.f;
#pragma unroll
  for (int i = 0; i < 14; ++i) if (i < sz) msum += acc[i];
  mol[(size_t)m * HH + tid] = msum;
}

// ---------------------------------------------------------------------------
// mpnn_emb^T[h][d] = sum_m avg[d][m] * mol[m][h]   (stored transposed)
// ---------------------------------------------------------------------------
__global__ __launch_bounds__(256) void mpnn_emb_k(
    fp avg, const float* __restrict__ mol, float* __restrict__ embT)
{
  int d = blockIdx.x, tid = threadIdx.x;
  float acc = 0.f;
  for (int m = 0; m < NMOL_N; ++m)
    acc += avg[d * NMOL_N + m] * mol[(size_t)m * HH + tid];
  embT[(size_t)tid * LBL + d] = acc;
}

// ---------------------------------------------------------------------------
// fused GRU step (input projection + recurrence), both GRUs.
// grid = 512: g(2) x btile(16) x jtile(16); thread (bi,ji) does 6 dots.
// ---------------------------------------------------------------------------
__global__ __launch_bounds__(256) void gru_step(
    const float* __restrict__ hprev_c, const float* __restrict__ hprev_p,
    float* __restrict__ hnext_c, float* __restrict__ hnext_p,
    fp x_c, fp x_p, fp wih_c, fp whh_c, fp bih_c, fp bhh_c,
    fp wih_p, fp whh_p, fp bih_p, fp bhh_p,
    float* __restrict__ hcat_relu, const int* __restrict__ idxv, int t)
{
  int bx = blockIdx.x;
  int g = bx >> 8;
  int rem = bx & 255;
  int b0 = (rem >> 4) << 4;
  int j0 = (rem & 15) << 4;
  const float* hprev = g ? hprev_p : hprev_c;
  float* hnext = g ? hnext_p : hnext_c;
  fp x = g ? x_p : x_c;
  fp wih = g ? wih_p : wih_c;
  fp whh = g ? whh_p : whh_c;
  fp bih = g ? bih_p : bih_c;
  fp bhh = g ? bhh_p : bhh_c;

  __shared__ float hs[16][260];
  __shared__ float xs[16][132];
  int tid = threadIdx.x;
  for (int i = tid; i < 16 * HH; i += 256)
    hs[i >> 8][i & 255] = hprev[(size_t)b0 * HH + i];
  for (int i = tid; i < 16 * II; i += 256) {
    int bi2 = i >> 7, k = i & 127;
    xs[bi2][k] = x[((size_t)(b0 + bi2) * SS + t) * II + k];
  }
  __syncthreads();

  int ji = tid & 15, bi = tid >> 4;
  int b = b0 + bi, j = j0 + ji;
  const float* whr = whh + (size_t)j * HH;
  const float* whz = whr + HH * HH;
  const float* whn = whz + HH * HH;
  const float* wxr = wih + (size_t)j * II;
  const float* wxz = wxr + HH * II;
  const float* wxn = wxz + HH * II;
  const float* hvv = hs[bi];
  const float* xvv = xs[bi];

  float hr = 0.f, hz = 0.f, hn = 0.f;
  for (int k = 0; k < HH; k += 4) {
    float4 a = *(const float4*)(hvv + k);
    float4 r4 = *(const float4*)(whr + k);
    float4 z4 = *(const float4*)(whz + k);
    float4 n4 = *(const float4*)(whn + k);
    hr = fmaf(a.x, r4.x, hr); hr = fmaf(a.y, r4.y, hr);
    hr = fmaf(a.z, r4.z, hr); hr = fmaf(a.w, r4.w, hr);
    hz = fmaf(a.x, z4.x, hz); hz = fmaf(a.y, z4.y, hz);
    hz = fmaf(a.z, z4.z, hz); hz = fmaf(a.w, z4.w, hz);
    hn = fmaf(a.x, n4.x, hn); hn = fmaf(a.y, n4.y, hn);
    hn = fmaf(a.z, n4.z, hn); hn = fmaf(a.w, n4.w, hn);
  }
  float xr = 0.f, xz = 0.f, xn = 0.f;
  for (int k = 0; k < II; k += 4) {
    float4 a = *(const float4*)(xvv + k);
    float4 r4 = *(const float4*)(wxr + k);
    float4 z4 = *(const float4*)(wxz + k);
    float4 n4 = *(const float4*)(wxn + k);
    xr = fmaf(a.x, r4.x, xr); xr = fmaf(a.y, r4.y, xr);
    xr = fmaf(a.z, r4.z, xr); xr = fmaf(a.w, r4.w, xr);
    xz = fmaf(a.x, z4.x, xz); xz = fmaf(a.y, z4.y, xz);
    xz = fmaf(a.z, z4.z, xz); xz = fmaf(a.w, z4.w, xz);
    xn = fmaf(a.x, n4.x, xn); xn = fmaf(a.y, n4.y, xn);
    xn = fmaf(a.z, n4.z, xn); xn = fmaf(a.w, n4.w, xn);
  }
  xr += bih[j]; xz += bih[j + HH]; xn += bih[j + 2 * HH];
  hr += bhh[j]; hz += bhh[j + HH]; hn += bhh[j + 2 * HH];

  float r = sigm(xr + hr);
  float z = sigm(xz + hz);
  float n = tanhf(xn + r * hn);
  float hp = hvv[j];
  float hnew = (1.f - z) * n + z * hp;
  hnext[(size_t)b * HH + j] = hnew;
  if (t == idxv[b]) hcat_relu[(size_t)b * (2 * HH) + g * HH + j] = fmaxf(hnew, 0.f);
}

// ---------------------------------------------------------------------------
// fp32 GEMM for query: C[M,N] = A[M,K] @ W[K,N] + bias
// ---------------------------------------------------------------------------
__global__ __launch_bounds__(256) void gemm_f32(
    const float* __restrict__ A, fp W, fp bias, float* __restrict__ C,
    int M, int N, int K)
{
  int ntiles = N >> 4;
  int mt = blockIdx.x / ntiles, nt = blockIdx.x - mt * ntiles;
  int m0 = mt << 4, n0 = nt << 4;
  int tid = threadIdx.x;
  int ni = tid & 15, mi = tid >> 4;
  __shared__ float As[16][68];
  float acc = 0.f;
  for (int k0 = 0; k0 < K; k0 += 64) {
    __syncthreads();
    for (int i = tid; i < 1024; i += 256) {
      int r = i >> 6, kk = i & 63;
      As[r][kk] = A[(size_t)(m0 + r) * K + k0 + kk];
    }
    __syncthreads();
    const float* wp = W + (size_t)k0 * N + n0 + ni;
#pragma unroll 4
    for (int kk = 0; kk < 64; ++kk)
      acc = fmaf(As[mi][kk], wp[(size_t)kk * N], acc);
  }
  acc += bias[n0 + ni];
  C[(size_t)(m0 + mi) * N + n0 + ni] = acc;
}

// ---------------------------------------------------------------------------
// per-batch: match = sigmoid(q @ embT) ; x2 = match + match@w_out + b_out ;
// layernorm(200) -> mpnn_att
// ---------------------------------------------------------------------------
__global__ __launch_bounds__(256) void match_ln(
    const float* __restrict__ query, const float* __restrict__ embT,
    fp w_out, fp b_out, fp gamma, fp beta, float* __restrict__ matt)
{
  int b = blockIdx.x, tid = threadIdx.x;
  __shared__ float q[HH];
  __shared__ float mrow[LBL];
  __shared__ float red[256];
  q[tid] = query[(size_t)b * HH + tid];
  __syncthreads();
  if (tid < LBL) {
    float acc = 0.f;
    for (int k = 0; k < HH; ++k) acc += q[k] * embT[(size_t)k * LBL + tid];
    mrow[tid] = sigm(acc);
  }
  __syncthreads();
  float x2 = 0.f;
  if (tid < LBL) {
    float acc = b_out[tid] + mrow[tid];
    for (int jj = 0; jj < LBL; ++jj) acc += mrow[jj] * w_out[jj * LBL + tid];
    x2 = acc;
  }
  red[tid] = (tid < LBL) ? x2 : 0.f;
  __syncthreads();
  for (int s = 128; s > 0; s >>= 1) {
    if (tid < s) red[tid] += red[tid + s];
    __syncthreads();
  }
  float mu = red[0] / (float)LBL;
  __syncthreads();
  float dv = (tid < LBL) ? (x2 - mu) : 0.f;
  red[tid] = dv * dv;
  __syncthreads();
  for (int s = 128; s > 0; s >>= 1) {
    if (tid < s) red[tid] += red[tid + s];
    __syncthreads();
  }
  float var = red[0] / (float)LBL;
  if (tid < LBL) {
    float att = (x2 - mu) * rsqrtf(var + 1e-5f) * gamma[tid] + beta[tid];
    matt[(size_t)b * LBL + tid] = att;
  }
}

// ---------------------------------------------------------------------------
// per-batch: bip = q @ w_bip + b_bip ; bip_att = bip @ mw ; out = bip_att*matt
// ---------------------------------------------------------------------------
__global__ __launch_bounds__(256) void bip_out(
    const float* __restrict__ query, fp w_bip, fp b_bip,
    const float* __restrict__ mw, const float* __restrict__ matt,
    float* __restrict__ out)
{
  int b = blockIdx.x, tid = threadIdx.x;
  __shared__ float q[HH];
  __shared__ float bips[NSUBS];
  q[tid] = query[(size_t)b * HH + tid];
  __syncthreads();
  for (int s = tid; s < NSUBS; s += 256) {
    float acc = b_bip[s];
    for (int k = 0; k < HH; ++k) acc += q[k] * w_bip[(size_t)k * NSUBS + s];
    bips[s] = acc;
  }
  __syncthreads();
  if (tid < LBL) {
    float acc = 0.f;
    for (int s = 0; s < NSUBS; ++s) acc += bips[s] * mw[(size_t)s * LBL + tid];
    float vres = acc * matt[(size_t)b * LBL + tid];
    if (!(vres == vres)) vres = 0.f;     // NaN tripwire (no-op if correct)
    out[(size_t)b * LBL + tid] = vres;
  }
}

// ---------------------------------------------------------------------------
extern "C" void kernel_launch(void* const* d_in, const int* in_sizes, int n_in,
                              void* d_out, int out_size, void* d_ws, size_t ws_size,
                              hipStream_t stream)
{
  fp x_c   = (fp)d_in[0];
  fp x_p   = (fp)d_in[1];
  const int* mask = (const int*)d_in[2];
  fp wih_c = (fp)d_in[3];
  fp whh_c = (fp)d_in[4];
  fp bih_c = (fp)d_in[5];
  fp bhh_c = (fp)d_in[6];
  fp wih_p = (fp)d_in[7];
  fp whh_p = (fp)d_in[8];
  fp bih_p = (fp)d_in[9];
  fp bhh_p = (fp)d_in[10];
  fp w_query = (fp)d_in[11];
  fp b_query = (fp)d_in[12];
  fp w_bip = (fp)d_in[13];
  fp b_bip = (fp)d_in[14];
  fp w_masklin = (fp)d_in[15];
  fp ddi = (fp)d_in[16];
  fp embed_fp = (fp)d_in[17];
  const int* fingerprints = (const int*)d_in[18];
  fp adj = (fp)d_in[19];
  const int* seg = (const int*)d_in[20];
  fp w_g0 = (fp)d_in[21];
  fp b_g0 = (fp)d_in[22];
  fp w_g1 = (fp)d_in[23];
  fp b_g1 = (fp)d_in[24];
  fp avg = (fp)d_in[25];
  fp w_out = (fp)d_in[26];
  fp b_out = (fp)d_in[27];
  fp gamma = (fp)d_in[28];
  fp beta = (fp)d_in[29];
  float* out = (float*)d_out;

  char* w = (char*)d_ws;
  size_t off = 0;
  auto alloc = [&](size_t bytes) -> void* {
    void* p = w + off;
    off = (off + bytes + 255) & ~(size_t)255;
    return p;
  };

  // total ~3.26 MB
  float* mol  = (float*)alloc((size_t)NMOL_N * HH * 4);
  float* embT = (float*)alloc((size_t)HH * LBL * 4);
  float* hbuf = (float*)alloc((size_t)4 * 65536 * 4);
  float* hcat = (float*)alloc((size_t)BB * 2 * HH * 4);
  float* query = (float*)alloc((size_t)BB * HH * 4);
  float* matt = (float*)alloc((size_t)BB * LBL * 4);
  float* mw   = (float*)alloc((size_t)NSUBS * LBL * 4);
  int* idxv   = (int*)alloc(256 * 4);
  int* mstart = (int*)alloc((NMOL_N + 1) * 4);

  float* h_c0 = hbuf;
  float* h_c1 = hbuf + 65536;
  float* h_p0 = hbuf + 2 * 65536;
  float* h_p1 = hbuf + 3 * 65536;

  prep_kernel<<<10, 256, 0, stream>>>(mask, idxv, seg, mstart, w_masklin, ddi,
                                      mw, hbuf);

  mpnn_mol<<<NMOL_N, 256, 0, stream>>>(fingerprints, embed_fp, adj, mstart,
                                       w_g0, b_g0, w_g1, b_g1, mol);
  mpnn_emb_k<<<LBL, 256, 0, stream>>>(avg, mol, embT);

  for (int t = 0; t < SS; ++t) {
    const float* hin_c = (t & 1) ? h_c1 : h_c0;
    float* hout_c = (t & 1) ? h_c0 : h_c1;
    const float* hin_p = (t & 1) ? h_p1 : h_p0;
    float* hout_p = (t & 1) ? h_p0 : h_p1;
    gru_step<<<512, 256, 0, stream>>>(hin_c, hin_p, hout_c, hout_p, x_c, x_p,
                                      wih_c, whh_c, bih_c, bhh_c,
                                      wih_p, whh_p, bih_p, bhh_p,
                                      hcat, idxv, t);
  }

  gemm_f32<<<256, 256, 0, stream>>>(hcat, w_query, b_query, query, BB, HH, 2 * HH);
  match_ln<<<BB, 256, 0, stream>>>(query, embT, w_out, b_out, gamma, beta, matt);
  bip_out<<<BB, 256, 0, stream>>>(query, w_bip, b_bip, mw, matt, out);
}

// Round 5
// 1357.633 us; speedup vs baseline: 2.0572x; 2.0572x over previous
//
#include <hip/hip_runtime.h>
#include <hip/hip_bf16.h>

#define BB 256
#define SS 32
#define II 128
#define HH 256
#define LBL 200
#define NSUBS 491
#define NATOMS_N 8000
#define NMOL_N 600

typedef const float* fp;

__device__ __forceinline__ float sigm(float x) { return 1.f / (1.f + expf(-x)); }

// ---------------------------------------------------------------------------
// prep: blocks 0..9 as round 4; blocks 10..2313 build transposed weights
// wT3[g][k(384)][gate(3)][j(256)]; k<256 -> w_hh[gate*256+j][k],
// k>=256 -> w_ih[gate*256+j][k-256]
// ---------------------------------------------------------------------------
__global__ __launch_bounds__(256) void prep_kernel(
    const int* __restrict__ mask, int* __restrict__ idxv,
    const int* __restrict__ seg, int* __restrict__ mstart,
    fp w_masklin, fp ddi, float* __restrict__ mw,
    float* __restrict__ hzero,
    fp whh_c, fp wih_c, fp whh_p, fp wih_p, float* __restrict__ wT3)
{
  int bx = blockIdx.x, tid = threadIdx.x;
  if (bx == 0) {                         // idx[b] = clamp(sum(mask[b,:]) - 1)
    int s = 0;
    const int* mrow = mask + tid * SS;
    for (int t = 0; t < SS; ++t) s += mrow[t];
    s -= 1;
    if (s < 0) s = 0;
    if (s > SS - 1) s = SS - 1;
    idxv[tid] = s;
  } else if (bx == 1) {                  // mstart[m] = lower_bound(seg, m)
    for (int m = tid; m <= NMOL_N; m += 256) {
      if (m == NMOL_N) { mstart[m] = NATOMS_N; continue; }
      int lo = 0, hi = NATOMS_N;
      while (lo < hi) {
        int mid = (lo + hi) >> 1;
        if (seg[mid] < m) lo = mid + 1; else hi = mid;
      }
      mstart[m] = lo;
    }
  } else if (bx < 6) {                   // mw[s][l] = w_masklin[s][l]*ddi[l][s]
    for (int o = (bx - 2) * 256 + tid; o < NSUBS * LBL; o += 4 * 256) {
      int s = o / LBL, l = o - s * LBL;
      mw[o] = w_masklin[o] * ddi[l * NSUBS + s];
    }
  } else if (bx < 10) {                  // zero 4 h buffers (65536 floats each)
    float* p = hzero + (size_t)(bx - 6) * 65536;
    for (int o = tid; o < 65536; o += 256) p[o] = 0.f;
  } else {                               // weight transpose, one (g,k,gate) row
    int lin = bx - 10;                   // lin = (g*384 + k)*3 + gate
    int g = lin / 1152;
    int rem = lin - g * 1152;
    int k = rem / 3;
    int gate = rem - k * 3;
    int n = gate * 256 + tid;            // source row
    float val;
    if (k < 256) {
      fp whh = g ? whh_p : whh_c;
      val = whh[(size_t)n * HH + k];
    } else {
      fp wih = g ? wih_p : wih_c;
      val = wih[(size_t)n * II + (k - 256)];
    }
    wT3[(size_t)lin * 256 + tid] = val;
  }
}

// ---------------------------------------------------------------------------
// fully-fused MPNN: one block per molecule (<=14 atoms).
// ---------------------------------------------------------------------------
__global__ __launch_bounds__(256) void mpnn_mol(
    const int* __restrict__ fingerprints, fp embed_fp, fp adj,
    const int* __restrict__ mstart, fp w_g0, fp b_g0, fp w_g1, fp b_g1,
    float* __restrict__ mol)
{
  int m = blockIdx.x, tid = threadIdx.x;
  int a0 = mstart[m], a1 = mstart[m + 1];
  int sz = a1 - a0;
  if (sz < 0) sz = 0;
  if (sz > 14) sz = 14;

  __shared__ float v[14][260];
  __shared__ float adjb[14][16];

#pragma unroll
  for (int i = 0; i < 14; ++i) {
    float val = 0.f;
    if (i < sz) {
      int f = fingerprints[a0 + i] & 1023;
      val = embed_fp[(size_t)f * HH + tid];
    }
    v[i][tid] = val;
  }
  if (tid < 224) {
    int i = tid >> 4, jj = tid & 15;
    float a = 0.f;
    if (i < sz && jj < sz)
      a = adj[(size_t)(a0 + i) * NATOMS_N + a0 + jj];
    adjb[i][jj] = a;
  }
  __syncthreads();

  float acc[14];
  for (int rd = 0; rd < 2; ++rd) {
    const float* wp0 = (rd ? w_g1 : w_g0) + tid;
#pragma unroll
    for (int i = 0; i < 14; ++i) acc[i] = 0.f;
    for (int k = 0; k < HH; k += 4) {
      float w0 = wp0[(size_t)k * HH];
      float w1 = wp0[(size_t)(k + 1) * HH];
      float w2 = wp0[(size_t)(k + 2) * HH];
      float w3 = wp0[(size_t)(k + 3) * HH];
#pragma unroll
      for (int i = 0; i < 14; ++i) {
        float4 vv = *(const float4*)&v[i][k];
        acc[i] = fmaf(vv.x, w0, acc[i]);
        acc[i] = fmaf(vv.y, w1, acc[i]);
        acc[i] = fmaf(vv.z, w2, acc[i]);
        acc[i] = fmaf(vv.w, w3, acc[i]);
      }
    }
    float bias = (rd ? b_g1 : b_g0)[tid];
    float hreg[14];
#pragma unroll
    for (int i = 0; i < 14; ++i) hreg[i] = fmaxf(acc[i] + bias, 0.f);
#pragma unroll
    for (int i = 0; i < 14; ++i) {
      float s = hreg[i];
#pragma unroll
      for (int jj = 0; jj < 14; ++jj) s = fmaf(adjb[i][jj], hreg[jj], s);
      acc[i] = s;
    }
    if (rd == 0) {
      __syncthreads();
#pragma unroll
      for (int i = 0; i < 14; ++i) v[i][tid] = acc[i];
      __syncthreads();
    }
  }
  float msum = 0.f;
#pragma unroll
  for (int i = 0; i < 14; ++i) if (i < sz) msum += acc[i];
  mol[(size_t)m * HH + tid] = msum;
}

// ---------------------------------------------------------------------------
// mpnn_emb^T[h][d] = sum_m avg[d][m] * mol[m][h]
// ---------------------------------------------------------------------------
__global__ __launch_bounds__(256) void mpnn_emb_k(
    fp avg, const float* __restrict__ mol, float* __restrict__ embT)
{
  int d = blockIdx.x, tid = threadIdx.x;
  float acc = 0.f;
  for (int m = 0; m < NMOL_N; ++m)
    acc += avg[d * NMOL_N + m] * mol[(size_t)m * HH + tid];
  embT[(size_t)tid * LBL + d] = acc;
}

// ---------------------------------------------------------------------------
// fused GRU step v2: transposed weights wT3[g][k][gate][j], coalesced 64B
// lines, scalar per-lane weight reads. grid = 512: g(2) x btile(16) x jtile(16)
// accumulators: sr,sz fused (x+h); shn (h-part of n), sxn (x-part of n).
// ---------------------------------------------------------------------------
__global__ __launch_bounds__(256) void gru_step(
    const float* __restrict__ hprev_c, const float* __restrict__ hprev_p,
    float* __restrict__ hnext_c, float* __restrict__ hnext_p,
    fp x_c, fp x_p, const float* __restrict__ wT3,
    fp bih_c, fp bhh_c, fp bih_p, fp bhh_p,
    float* __restrict__ hcat_relu, const int* __restrict__ idxv, int t)
{
  int bx = blockIdx.x;
  int g = bx >> 8;
  int rem = bx & 255;
  int b0 = (rem >> 4) << 4;
  int j0 = (rem & 15) << 4;
  const float* hprev = g ? hprev_p : hprev_c;
  float* hnext = g ? hnext_p : hnext_c;
  fp x = g ? x_p : x_c;
  fp bih = g ? bih_p : bih_c;
  fp bhh = g ? bhh_p : bhh_c;

  __shared__ float hs[16][260];
  __shared__ float xs[16][132];
  int tid = threadIdx.x;
  for (int i = tid; i < 16 * HH; i += 256)
    hs[i >> 8][i & 255] = hprev[(size_t)b0 * HH + i];
  for (int i = tid; i < 16 * II; i += 256) {
    int bi2 = i >> 7, k = i & 127;
    xs[bi2][k] = x[((size_t)(b0 + bi2) * SS + t) * II + k];
  }
  __syncthreads();

  int ji = tid & 15, bi = tid >> 4;
  int b = b0 + bi, j = j0 + ji;
  const float* w = wT3 + (size_t)g * 384 * 768 + j0 + ji;  // + k*768 + gate*256
  const float* hv = hs[bi];
  const float* xv = xs[bi];

  float sr = 0.f, sz = 0.f, shn = 0.f, sxn = 0.f;
#pragma unroll 8
  for (int k = 0; k < HH; ++k) {
    float h = hv[k];
    const float* wk = w + (size_t)k * 768;
    sr  = fmaf(h, wk[0],   sr);
    sz  = fmaf(h, wk[256], sz);
    shn = fmaf(h, wk[512], shn);
  }
#pragma unroll 8
  for (int k = 0; k < II; ++k) {
    float xval = xv[k];
    const float* wk = w + (size_t)(256 + k) * 768;
    sr  = fmaf(xval, wk[0],   sr);
    sz  = fmaf(xval, wk[256], sz);
    sxn = fmaf(xval, wk[512], sxn);
  }

  float r = sigm(sr + bih[j] + bhh[j]);
  float z = sigm(sz + bih[j + 256] + bhh[j + 256]);
  float n = tanhf(sxn + bih[j + 512] + r * (shn + bhh[j + 512]));
  float hp = hv[j];
  float hnew = (1.f - z) * n + z * hp;
  hnext[(size_t)b * HH + j] = hnew;
  if (t == idxv[b]) hcat_relu[(size_t)b * (2 * HH) + g * HH + j] = fmaxf(hnew, 0.f);
}

// ---------------------------------------------------------------------------
// fp32 GEMM for query: C[M,N] = A[M,K] @ W[K,N] + bias
// ---------------------------------------------------------------------------
__global__ __launch_bounds__(256) void gemm_f32(
    const float* __restrict__ A, fp W, fp bias, float* __restrict__ C,
    int M, int N, int K)
{
  int ntiles = N >> 4;
  int mt = blockIdx.x / ntiles, nt = blockIdx.x - mt * ntiles;
  int m0 = mt << 4, n0 = nt << 4;
  int tid = threadIdx.x;
  int ni = tid & 15, mi = tid >> 4;
  __shared__ float As[16][68];
  float acc = 0.f;
  for (int k0 = 0; k0 < K; k0 += 64) {
    __syncthreads();
    for (int i = tid; i < 1024; i += 256) {
      int r = i >> 6, kk = i & 63;
      As[r][kk] = A[(size_t)(m0 + r) * K + k0 + kk];
    }
    __syncthreads();
    const float* wp = W + (size_t)k0 * N + n0 + ni;
#pragma unroll 4
    for (int kk = 0; kk < 64; ++kk)
      acc = fmaf(As[mi][kk], wp[(size_t)kk * N], acc);
  }
  acc += bias[n0 + ni];
  C[(size_t)(m0 + mi) * N + n0 + ni] = acc;
}

// ---------------------------------------------------------------------------
// per-batch: match = sigmoid(q @ embT) ; x2 = match + match@w_out + b_out ;
// layernorm(200) -> mpnn_att
// ---------------------------------------------------------------------------
__global__ __launch_bounds__(256) void match_ln(
    const float* __restrict__ query, const float* __restrict__ embT,
    fp w_out, fp b_out, fp gamma, fp beta, float* __restrict__ matt)
{
  int b = blockIdx.x, tid = threadIdx.x;
  __shared__ float q[HH];
  __shared__ float mrow[LBL];
  __shared__ float red[256];
  q[tid] = query[(size_t)b * HH + tid];
  __syncthreads();
  if (tid < LBL) {
    float acc = 0.f;
    for (int k = 0; k < HH; ++k) acc += q[k] * embT[(size_t)k * LBL + tid];
    mrow[tid] = sigm(acc);
  }
  __syncthreads();
  float x2 = 0.f;
  if (tid < LBL) {
    float acc = b_out[tid] + mrow[tid];
    for (int jj = 0; jj < LBL; ++jj) acc += mrow[jj] * w_out[jj * LBL + tid];
    x2 = acc;
  }
  red[tid] = (tid < LBL) ? x2 : 0.f;
  __syncthreads();
  for (int s = 128; s > 0; s >>= 1) {
    if (tid < s) red[tid] += red[tid + s];
    __syncthreads();
  }
  float mu = red[0] / (float)LBL;
  __syncthreads();
  float dv = (tid < LBL) ? (x2 - mu) : 0.f;
  red[tid] = dv * dv;
  __syncthreads();
  for (int s = 128; s > 0; s >>= 1) {
    if (tid < s) red[tid] += red[tid + s];
    __syncthreads();
  }
  float var = red[0] / (float)LBL;
  if (tid < LBL) {
    float att = (x2 - mu) * rsqrtf(var + 1e-5f) * gamma[tid] + beta[tid];
    matt[(size_t)b * LBL + tid] = att;
  }
}

// ---------------------------------------------------------------------------
// per-batch: bip = q @ w_bip + b_bip ; bip_att = bip @ mw ; out = bip_att*matt
// ---------------------------------------------------------------------------
__global__ __launch_bounds__(256) void bip_out(
    const float* __restrict__ query, fp w_bip, fp b_bip,
    const float* __restrict__ mw, const float* __restrict__ matt,
    float* __restrict__ out)
{
  int b = blockIdx.x, tid = threadIdx.x;
  __shared__ float q[HH];
  __shared__ float bips[NSUBS];
  q[tid] = query[(size_t)b * HH + tid];
  __syncthreads();
  for (int s = tid; s < NSUBS; s += 256) {
    float acc = b_bip[s];
    for (int k = 0; k < HH; ++k) acc += q[k] * w_bip[(size_t)k * NSUBS + s];
    bips[s] = acc;
  }
  __syncthreads();
  if (tid < LBL) {
    float acc = 0.f;
    for (int s = 0; s < NSUBS; ++s) acc += bips[s] * mw[(size_t)s * LBL + tid];
    float vres = acc * matt[(size_t)b * LBL + tid];
    if (!(vres == vres)) vres = 0.f;     // NaN tripwire (no-op if correct)
    out[(size_t)b * LBL + tid] = vres;
  }
}

// ---------------------------------------------------------------------------
extern "C" void kernel_launch(void* const* d_in, const int* in_sizes, int n_in,
                              void* d_out, int out_size, void* d_ws, size_t ws_size,
                              hipStream_t stream)
{
  fp x_c   = (fp)d_in[0];
  fp x_p   = (fp)d_in[1];
  const int* mask = (const int*)d_in[2];
  fp wih_c = (fp)d_in[3];
  fp whh_c = (fp)d_in[4];
  fp bih_c = (fp)d_in[5];
  fp bhh_c = (fp)d_in[6];
  fp wih_p = (fp)d_in[7];
  fp whh_p = (fp)d_in[8];
  fp bih_p = (fp)d_in[9];
  fp bhh_p = (fp)d_in[10];
  fp w_query = (fp)d_in[11];
  fp b_query = (fp)d_in[12];
  fp w_bip = (fp)d_in[13];
  fp b_bip = (fp)d_in[14];
  fp w_masklin = (fp)d_in[15];
  fp ddi = (fp)d_in[16];
  fp embed_fp = (fp)d_in[17];
  const int* fingerprints = (const int*)d_in[18];
  fp adj = (fp)d_in[19];
  const int* seg = (const int*)d_in[20];
  fp w_g0 = (fp)d_in[21];
  fp b_g0 = (fp)d_in[22];
  fp w_g1 = (fp)d_in[23];
  fp b_g1 = (fp)d_in[24];
  fp avg = (fp)d_in[25];
  fp w_out = (fp)d_in[26];
  fp b_out = (fp)d_in[27];
  fp gamma = (fp)d_in[28];
  fp beta = (fp)d_in[29];
  float* out = (float*)d_out;

  char* w = (char*)d_ws;
  size_t off = 0;
  auto alloc = [&](size_t bytes) -> void* {
    void* p = w + off;
    off = (off + bytes + 255) & ~(size_t)255;
    return p;
  };

  float* mol  = (float*)alloc((size_t)NMOL_N * HH * 4);
  float* embT = (float*)alloc((size_t)HH * LBL * 4);
  float* hbuf = (float*)alloc((size_t)4 * 65536 * 4);
  float* hcat = (float*)alloc((size_t)BB * 2 * HH * 4);
  float* query = (float*)alloc((size_t)BB * HH * 4);
  float* matt = (float*)alloc((size_t)BB * LBL * 4);
  float* mw   = (float*)alloc((size_t)NSUBS * LBL * 4);
  float* wT3  = (float*)alloc((size_t)2 * 384 * 768 * 4);   // 2.36 MB
  int* idxv   = (int*)alloc(256 * 4);
  int* mstart = (int*)alloc((NMOL_N + 1) * 4);

  float* h_c0 = hbuf;
  float* h_c1 = hbuf + 65536;
  float* h_p0 = hbuf + 2 * 65536;
  float* h_p1 = hbuf + 3 * 65536;

  prep_kernel<<<10 + 2304, 256, 0, stream>>>(mask, idxv, seg, mstart,
                                             w_masklin, ddi, mw, hbuf,
                                             whh_c, wih_c, whh_p, wih_p, wT3);

  mpnn_mol<<<NMOL_N, 256, 0, stream>>>(fingerprints, embed_fp, adj, mstart,
                                       w_g0, b_g0, w_g1, b_g1, mol);
  mpnn_emb_k<<<LBL, 256, 0, stream>>>(avg, mol, embT);

  for (int t = 0; t < SS; ++t) {
    const float* hin_c = (t & 1) ? h_c1 : h_c0;
    float* hout_c = (t & 1) ? h_c0 : h_c1;
    const float* hin_p = (t & 1) ? h_p1 : h_p0;
    float* hout_p = (t & 1) ? h_p0 : h_p1;
    gru_step<<<512, 256, 0, stream>>>(hin_c, hin_p, hout_c, hout_p, x_c, x_p,
                                      wT3, bih_c, bhh_c, bih_p, bhh_p,
                                      hcat, idxv, t);
  }

  gemm_f32<<<256, 256, 0, stream>>>(hcat, w_query, b_query, query, BB, HH, 2 * HH);
  match_ln<<<BB, 256, 0, stream>>>(query, embT, w_out, b_out, gamma, beta, matt);
  bip_out<<<BB, 256, 0, stream>>>(query, w_bip, b_bip, mw, matt, out);
}